// Round 1
// baseline (297.240 us; speedup 1.0000x reference)
//
#include <hip/hip_runtime.h>
#include <hip/hip_bf16.h>

// Problem constants (derived defensively from in_sizes at launch):
// N=10000 nodes, E=50000 edges, IN=32, H=64.
//
// Algebraic refactor: theta[e,i,o] = sum_k ea[e,k]*nn_w[k,i*64+o] + nn_b[i*64+o]
//   => msg[e,o] = sum_k ea[e,k]*Zk[src,o] + Zb[src,o]
// where Zk = out @ W_k, Zb = out @ B.  So per iteration:
//   ZZ[N,576] = out @ [W0|W1|W2|W3|B|root_w|w_hh^T]   (gh hoisted: h==out)
//   agg = scatter_add(dst, weighted gather of ZZ[src, 0:320])
//   m = relu(agg + ZZ[:,320:384] + conv_b); gi = m @ w_ih^T; GRU elementwise.

#define LDSP 68  // padded LDS row stride (floats): keeps float4 alignment, bank-friendly

__device__ __forceinline__ float sigmoidf_(float x) {
    return 1.0f / (1.0f + __expf(-x));
}
__device__ __forceinline__ float tanhf_(float x) {
    // tanh(x) = 2/(1+exp(-2x)) - 1 ; correct limits at +-inf
    return 2.0f / (1.0f + __expf(-2.0f * x)) - 1.0f;
}

// ---------------- lin0: out = relu(x @ lin0_w + b), x:[N,32], w:[32,64] -------------
__global__ __launch_bounds__(256) void lin0_k(const float* __restrict__ x,
                                              const float* __restrict__ w,
                                              const float* __restrict__ b,
                                              float* __restrict__ h, int N) {
    int gid = blockIdx.x * 256 + threadIdx.x;
    int n = gid >> 6, l = gid & 63;
    if (n >= N) return;
    float acc = b[l];
#pragma unroll
    for (int j = 0; j < 32; ++j) acc = fmaf(x[n * 32 + j], w[j * 64 + l], acc);
    h[n * 64 + l] = fmaxf(acc, 0.0f);
}

// ---------------- kernel A: ZZ[N,576] = h[N,64] @ Wcat[64,576] ----------------------
// col-blocks (blockIdx.y): 0..3 -> nn_w k ; 4 -> nn_b ; 5 -> root_w ; 6..8 -> w_hh^T
__global__ __launch_bounds__(256) void gemm_a(const float* __restrict__ h,
                                              const float* __restrict__ nn_w,
                                              const float* __restrict__ nn_b,
                                              const float* __restrict__ root_w,
                                              const float* __restrict__ w_hh,
                                              float* __restrict__ ZZ, int N) {
    __shared__ float a_lds[64 * LDSP];
    __shared__ float w_lds[64 * LDSP];
    const int n0 = blockIdx.x * 64;
    const int cb = blockIdx.y;
    const int tid = threadIdx.x;

    // stage h rows transposed: a_lds[j][r] = h[n0+r, j]
    for (int idx = tid; idx < 4096; idx += 256) {
        int r = idx >> 6, j = idx & 63;
        int n = n0 + r;
        a_lds[j * LDSP + r] = (n < N) ? h[n * 64 + j] : 0.0f;
    }
    // stage weight tile: w_lds[j][c] = Wcat[j, cb*64+c]
    if (cb < 6) {
        for (int idx = tid; idx < 4096; idx += 256) {
            int j = idx >> 6, c = idx & 63;  // c fastest -> coalesced global reads
            float v;
            if (cb < 4) v = nn_w[cb * 4096 + j * 64 + c];
            else if (cb == 4) v = nn_b[j * 64 + c];
            else v = root_w[j * 64 + c];
            w_lds[j * LDSP + c] = v;
        }
    } else {
        int g0 = (cb - 6) * 64;
        for (int idx = tid; idx < 4096; idx += 256) {
            int c = idx >> 6, j = idx & 63;  // j fastest -> coalesced reads of w_hh rows
            w_lds[j * LDSP + c] = w_hh[(g0 + c) * 64 + j];
        }
    }
    __syncthreads();

    const int row_t = tid >> 4, col_t = tid & 15;
    const int r0 = row_t * 4, c0 = col_t * 4;
    float acc[4][4] = {};
#pragma unroll 8
    for (int j = 0; j < 64; ++j) {
        const float4 a = *(const float4*)(a_lds + j * LDSP + r0);
        const float4 w = *(const float4*)(w_lds + j * LDSP + c0);
        const float av[4] = {a.x, a.y, a.z, a.w};
        const float wv[4] = {w.x, w.y, w.z, w.w};
#pragma unroll
        for (int rr = 0; rr < 4; ++rr)
#pragma unroll
            for (int cc = 0; cc < 4; ++cc) acc[rr][cc] = fmaf(av[rr], wv[cc], acc[rr][cc]);
    }
    const int cbase = cb * 64 + c0;
#pragma unroll
    for (int rr = 0; rr < 4; ++rr) {
        int n = n0 + r0 + rr;
        if (n < N) {
            float4 v = make_float4(acc[rr][0], acc[rr][1], acc[rr][2], acc[rr][3]);
            *(float4*)(ZZ + (size_t)n * 576 + cbase) = v;
        }
    }
}

// ---------------- kernel B: edge gather + scatter-add -------------------------------
__global__ __launch_bounds__(256) void scatter_k(const int* __restrict__ ei,
                                                 const float* __restrict__ ea,
                                                 const float* __restrict__ ZZ,
                                                 float* __restrict__ agg, int E) {
    int e = blockIdx.x * 4 + (threadIdx.x >> 6);
    int lane = threadIdx.x & 63;
    if (e >= E) return;
    int s = ei[e];
    int d = ei[E + e];
    const float4 a = *(const float4*)(ea + (size_t)e * 4);
    const float* z = ZZ + (size_t)s * 576;
    float v = z[256 + lane];
    v = fmaf(a.x, z[lane], v);
    v = fmaf(a.y, z[64 + lane], v);
    v = fmaf(a.z, z[128 + lane], v);
    v = fmaf(a.w, z[192 + lane], v);
    atomicAdd(agg + (size_t)d * 64 + lane, v);
}

// ---------------- kernel C: fused m -> gi GEMM -> GRU elementwise -------------------
__global__ __launch_bounds__(256) void gru_fused(const float* __restrict__ agg,
                                                 const float* __restrict__ ZZ,
                                                 const float* __restrict__ conv_b,
                                                 const float* __restrict__ w_ih,
                                                 const float* __restrict__ b_ih,
                                                 const float* __restrict__ b_hh,
                                                 float* __restrict__ h,
                                                 float* __restrict__ out_final, int N) {
    __shared__ float m_lds[64 * LDSP];
    __shared__ float w_lds[64 * LDSP];
    const int n0 = blockIdx.x * 64;
    const int tid = threadIdx.x;

    // stage m transposed: m_lds[j][r] = relu(agg[n,j] + R[n,j] + conv_b[j])
    for (int idx = tid; idx < 4096; idx += 256) {
        int r = idx >> 6, j = idx & 63;
        int n = n0 + r;
        float v = 0.0f;
        if (n < N) {
            v = agg[n * 64 + j] + ZZ[(size_t)n * 576 + 320 + j] + conv_b[j];
            v = fmaxf(v, 0.0f);
        }
        m_lds[j * LDSP + r] = v;
    }

    const int row_t = tid >> 4, col_t = tid & 15;
    const int r0 = row_t * 4, c0 = col_t * 4;
    float acc[3][4][4] = {};
#pragma unroll
    for (int cb = 0; cb < 3; ++cb) {
        __syncthreads();  // also covers m_lds staging on first pass; protects w_lds reuse
        for (int idx = tid; idx < 4096; idx += 256) {
            int c = idx >> 6, j = idx & 63;  // j fastest -> coalesced w_ih row reads
            w_lds[j * LDSP + c] = w_ih[(cb * 64 + c) * 64 + j];
        }
        __syncthreads();
#pragma unroll 8
        for (int j = 0; j < 64; ++j) {
            const float4 a = *(const float4*)(m_lds + j * LDSP + r0);
            const float4 w = *(const float4*)(w_lds + j * LDSP + c0);
            const float av[4] = {a.x, a.y, a.z, a.w};
            const float wv[4] = {w.x, w.y, w.z, w.w};
#pragma unroll
            for (int rr = 0; rr < 4; ++rr)
#pragma unroll
                for (int cc = 0; cc < 4; ++cc)
                    acc[cb][rr][cc] = fmaf(av[rr], wv[cc], acc[cb][rr][cc]);
        }
    }

    // epilogue: GRU elementwise, each thread owns rows r0..r0+3, cols c0..c0+3
#pragma unroll
    for (int rr = 0; rr < 4; ++rr) {
        int n = n0 + r0 + rr;
        if (n >= N) continue;
        const float4 ghr4 = *(const float4*)(ZZ + (size_t)n * 576 + 384 + c0);
        const float4 ghz4 = *(const float4*)(ZZ + (size_t)n * 576 + 448 + c0);
        const float4 ghn4 = *(const float4*)(ZZ + (size_t)n * 576 + 512 + c0);
        const float4 hv4 = *(const float4*)(h + (size_t)n * 64 + c0);
        const float ghr[4] = {ghr4.x, ghr4.y, ghr4.z, ghr4.w};
        const float ghz[4] = {ghz4.x, ghz4.y, ghz4.z, ghz4.w};
        const float ghn[4] = {ghn4.x, ghn4.y, ghn4.z, ghn4.w};
        const float hv[4] = {hv4.x, hv4.y, hv4.z, hv4.w};
        float hnew[4];
#pragma unroll
        for (int cc = 0; cc < 4; ++cc) {
            int l = c0 + cc;
            float gir = acc[0][rr][cc] + b_ih[l];
            float giz = acc[1][rr][cc] + b_ih[64 + l];
            float gin = acc[2][rr][cc] + b_ih[128 + l];
            float hr = ghr[cc] + b_hh[l];
            float hz = ghz[cc] + b_hh[64 + l];
            float hn = ghn[cc] + b_hh[128 + l];
            float rg = sigmoidf_(gir + hr);
            float zg = sigmoidf_(giz + hz);
            float ng = tanhf_(gin + rg * hn);
            hnew[cc] = (1.0f - zg) * ng + zg * hv[cc];
        }
        float4 o = make_float4(hnew[0], hnew[1], hnew[2], hnew[3]);
        *(float4*)(h + (size_t)n * 64 + c0) = o;
        if (out_final) *(float4*)(out_final + (size_t)n * 64 + c0) = o;
    }
}

extern "C" void kernel_launch(void* const* d_in, const int* in_sizes, int n_in,
                              void* d_out, int out_size, void* d_ws, size_t ws_size,
                              hipStream_t stream) {
    const float* x      = (const float*)d_in[0];
    const int*   ei     = (const int*)d_in[1];
    const float* ea     = (const float*)d_in[2];
    const float* lin0_w = (const float*)d_in[3];
    const float* lin0_b = (const float*)d_in[4];
    const float* nn_w   = (const float*)d_in[5];
    const float* nn_b   = (const float*)d_in[6];
    const float* root_w = (const float*)d_in[7];
    const float* conv_b = (const float*)d_in[8];
    const float* gw_ih  = (const float*)d_in[9];
    const float* gw_hh  = (const float*)d_in[10];
    const float* gb_ih  = (const float*)d_in[11];
    const float* gb_hh  = (const float*)d_in[12];

    const int N = in_sizes[0] / 32;
    const int E = in_sizes[1] / 2;

    float* h   = (float*)d_ws;                 // [N,64]
    float* ZZ  = h + (size_t)N * 64;           // [N,576]
    float* agg = ZZ + (size_t)N * 576;         // [N,64]

    const int RB = (N + 63) / 64;

    lin0_k<<<(N * 64 + 255) / 256, 256, 0, stream>>>(x, lin0_w, lin0_b, h, N);

    for (int it = 0; it < 3; ++it) {
        gemm_a<<<dim3(RB, 9), 256, 0, stream>>>(h, nn_w, nn_b, root_w, gw_hh, ZZ, N);
        hipMemsetAsync(agg, 0, (size_t)N * 64 * sizeof(float), stream);
        scatter_k<<<(E + 3) / 4, 256, 0, stream>>>(ei, ea, ZZ, agg, E);
        gru_fused<<<RB, 256, 0, stream>>>(agg, ZZ, conv_b, gw_ih, gb_ih, gb_hh, h,
                                          (it == 2) ? (float*)d_out : nullptr, N);
    }
}